// Round 10
// baseline (1169.694 us; speedup 1.0000x reference)
//
#include <hip/hip_runtime.h>
#include <hip/hip_bf16.h>
#include <math.h>
#include <stdint.h>

// Problem constants: B=4, T=2048, D=2048, E=4, H=8192, TOPK=2, CAP=N/E
#define N_TOK 8192
#define DMODEL 2048
#define NEXP 4
#define HDIM 8192
#define CAP 2048

typedef __attribute__((ext_vector_type(4))) float f32x4;
typedef __attribute__((ext_vector_type(8))) short s16x8;
typedef __attribute__((ext_vector_type(4))) unsigned short u16x4;

__device__ __forceinline__ unsigned short f2bf(float f) {
  __hip_bfloat16 h = __float2bfloat16(f);  // RNE
  return __builtin_bit_cast(unsigned short, h);
}

__device__ __forceinline__ void gload_lds16(const void* g, void* l) {
  __builtin_amdgcn_global_load_lds(
      (const __attribute__((address_space(1))) unsigned int*)(uintptr_t)g,
      (__attribute__((address_space(3))) unsigned int*)(unsigned int)(uintptr_t)l,
      16, 0, 0);
}

// ---------------- Router: logits = x @ Wg + bg (f64 accum), top-2 -> 64-bit sort keys --------
__global__ __launch_bounds__(256) void router_kernel(
    const float* __restrict__ x, const float* __restrict__ Wg,
    const float* __restrict__ bg, unsigned long long* __restrict__ keys) {
  int token = blockIdx.x * 4 + (threadIdx.x >> 6);
  int lane = threadIdx.x & 63;
  const float* xr = x + (size_t)token * DMODEL;
  double a0 = 0, a1 = 0, a2 = 0, a3 = 0;
  for (int i = lane; i < DMODEL; i += 64) {
    float xv = xr[i];
    float4 w = ((const float4*)Wg)[i];
    a0 += (double)xv * (double)w.x;
    a1 += (double)xv * (double)w.y;
    a2 += (double)xv * (double)w.z;
    a3 += (double)xv * (double)w.w;
  }
  for (int off = 32; off > 0; off >>= 1) {
    a0 += __shfl_down(a0, off);
    a1 += __shfl_down(a1, off);
    a2 += __shfl_down(a2, off);
    a3 += __shfl_down(a3, off);
  }
  if (lane == 0) {
    float l[4] = {(float)(a0 + (double)bg[0]), (float)(a1 + (double)bg[1]),
                  (float)(a2 + (double)bg[2]), (float)(a3 + (double)bg[3])};
    int e1 = 0;
    for (int e = 1; e < 4; ++e) if (l[e] > l[e1]) e1 = e;
    int e2 = (e1 == 0) ? 1 : 0;
    for (int e = e2 + 1; e < 4; ++e) { if (e == e1) continue; if (l[e] > l[e2]) e2 = e; }
    float d = l[e2] - l[e1];
    float ex = expf(d);
    float z = 1.0f + ex;
    float p1 = 1.0f / z, p2 = ex / z;
    unsigned lo = 0xFFFFFFFFu - (unsigned)token;
    for (int e = 0; e < 4; ++e) {
      unsigned hi = (e == e1) ? __float_as_uint(p1) : (e == e2) ? __float_as_uint(p2) : 0u;
      keys[(size_t)e * N_TOK + token] = ((unsigned long long)hi << 32) | lo;
    }
  }
}

// ---------------- Rank-based capacity selection: slot = #{j : key_j > key_i} -----------------
__global__ __launch_bounds__(256) void rank_select_kernel(
    const unsigned long long* __restrict__ keys, int* __restrict__ sel_idx,
    float* __restrict__ sel_p) {
  __shared__ unsigned long long kbuf[2048];  // 16 KiB
  const int e = blockIdx.y;
  const int i = blockIdx.x * 256 + threadIdx.x;
  const unsigned long long my = keys[(size_t)e * N_TOK + i];
  int rank = 0;
  for (int c = 0; c < N_TOK; c += 2048) {
    __syncthreads();
    for (int j = threadIdx.x; j < 2048; j += 256)
      kbuf[j] = keys[(size_t)e * N_TOK + c + j];
    __syncthreads();
#pragma unroll 8
    for (int j = 0; j < 2048; j += 2) {
      unsigned long long k0 = kbuf[j], k1 = kbuf[j + 1];
      rank += (k0 > my) + (k1 > my);
    }
  }
  if (rank < CAP) {
    sel_idx[e * CAP + rank] = i;
    sel_p[e * CAP + rank] = __uint_as_float((unsigned)(my >> 32));
  }
}

// ---------------- Gather selected token rows, f32 -> bf16 ----------------
__global__ __launch_bounds__(256) void gather_kernel(
    const float* __restrict__ x, const int* __restrict__ sel_idx,
    unsigned short* __restrict__ tok) {
  int row = blockIdx.x;
  int t = sel_idx[row];
  const float4* src = (const float4*)(x + (size_t)t * DMODEL);
  u16x4* dst = (u16x4*)(tok + (size_t)row * DMODEL);
  for (int i = threadIdx.x; i < DMODEL / 4; i += blockDim.x) {
    float4 v = src[i];
    u16x4 w = {f2bf(v.x), f2bf(v.y), f2bf(v.z), f2bf(v.w)};
    dst[i] = w;
  }
}

// ---------------- Transpose + convert: W[K][N] f32 -> WT[N][K] bf16, 64x64 tiles ----------------
__global__ __launch_bounds__(256) void transpose_convert_kernel(
    const float* __restrict__ W, unsigned short* __restrict__ WT, int K, int N) {
  __shared__ unsigned short tile[64][68];
  const size_t eoff = (size_t)blockIdx.z * (size_t)K * N;
  const float* Wp = W + eoff;
  unsigned short* Tp = WT + eoff;
  const int n0 = blockIdx.x * 64, k0 = blockIdx.y * 64;
  const int tid = threadIdx.x;
  const int nn4 = tid & 15, kk = tid >> 4;
#pragma unroll
  for (int p = 0; p < 4; ++p) {
    int k = kk + p * 16;
    float4 v = *(const float4*)&Wp[(size_t)(k0 + k) * N + n0 + nn4 * 4];
    tile[nn4 * 4 + 0][k] = f2bf(v.x);
    tile[nn4 * 4 + 1][k] = f2bf(v.y);
    tile[nn4 * 4 + 2][k] = f2bf(v.z);
    tile[nn4 * 4 + 3][k] = f2bf(v.w);
  }
  __syncthreads();
  const int nw = tid >> 4, cw = (tid & 15) * 4;
#pragma unroll
  for (int p = 0; p < 4; ++p) {
    int n = nw + p * 16;
    u16x4 v = *(const u16x4*)&tile[n][cw];
    *(u16x4*)&Tp[(size_t)(n0 + n) * K + k0 + cw] = v;
  }
}

// ---------------- m97-replica 128x128 bf16 GEMM, BK=32, 4 blocks/CU (TLP regime) ------------
// C[M,N] = A[M,K] * Bt[N,K]^T (both bf16, k-contiguous). 256 thr = 4 waves (2Mx2N),
// per-wave 64x64 = acc[4][4]. LDS single-buffered 16 KiB: A[128][32] + B[128][32] ->
// ~4 blocks/CU resident (the regime r3-r9 never reached: 1 blk/CU). Per K-tile:
// { 4 gload_lds -> __syncthreads (drains vmcnt) -> 8 ds_read_b128 + 16 MFMA ->
//   __syncthreads }. No explicit pipelining: cross-BLOCK TLP hides the stage drain
// (m114/m97: implicit wave-level overlap at 3-4 blk/CU ~= source pipelining).
// T2 chunk-XOR swizzle both sides (r8-verified 0 conflicts on [row][32] geometry):
// read chunk ^= (row>>1)&3, staging source chunk ^= same involution, linear LDS dest.
// EPI 0: exact GELU -> bf16. EPI 1: atomicAdd(out[sel_idx[m]], acc*sel_p[m]).
template <int EPI>
__global__ __launch_bounds__(256) void gemm_kernel(
    const unsigned short* __restrict__ A, const unsigned short* __restrict__ Bt,
    void* __restrict__ C, const int* __restrict__ sel_idx, const float* __restrict__ sel_p,
    int M, int N, int K, size_t b_stride) {
  __shared__ unsigned short sh[8192];  // A[128][32] @0, B[128][32] @4096 (ushorts)
  const int tid = threadIdx.x;
  const int lane = tid & 63;
  const int w = tid >> 6;            // wave 0..3
  const int wm = w >> 1, wn = w & 1; // 2M x 2N

  // XCD-aware bijective swizzle (nwg multiple of 8, gridDim.x power of 2)
  const int nwg = gridDim.x * gridDim.y;
  const int cpx = nwg >> 3;
  int linear = blockIdx.y * gridDim.x + blockIdx.x;
  linear = (linear & 7) * cpx + (linear >> 3);
  const int bx = linear & (gridDim.x - 1);
  const int by = linear >> __builtin_ctz(gridDim.x);
  const int m0 = by * 128, n0 = bx * 128;
  const unsigned short* Bp = Bt + (size_t)(m0 >> 11) * b_stride;

  f32x4 acc[4][4];
#pragma unroll
  for (int i = 0; i < 4; ++i)
#pragma unroll
    for (int j = 0; j < 4; ++j) acc[i][j] = (f32x4){0.f, 0.f, 0.f, 0.f};

  // Staging: round r covers rows r*64 + (w*16 + lane>>2); source 16B chunk
  // (lane&3)^((lane>>3)&3)  [involution of read swizzle; w*16, r*64 vanish mod 4 after >>1].
  const int srow = w * 16 + (lane >> 2);
  const int schunk = ((lane & 3) ^ ((lane >> 3) & 3)) * 8;
  const unsigned short* gA = A + (size_t)(m0 + srow) * K + schunk;
  const unsigned short* gB = Bp + (size_t)(n0 + srow) * K + schunk;
  const int ldsSt = w * 512;  // wave-uniform ushort offset within a 4KB round-half

  // Frag reads: row*32 + koff; koff = ((lane>>4) ^ ((lane>>1)&3)) chunks (lane-constant:
  // all row bases wm*64/wn*64/mf*16 are ≡0 mod 4 after >>1).
  const int arow = wm * 64 + (lane & 15);
  const int brow = wn * 64 + (lane & 15);
  const int koff = (((lane >> 4) ^ ((lane >> 1) & 3)) << 3);

  for (int kt = 0; kt < K; kt += 32) {
    // stage tile (4 gloads/thread: A rows 0-63, 64-127; B same)
    gload_lds16(gA + kt, &sh[ldsSt]);
    gload_lds16(gA + (size_t)64 * K + kt, &sh[2048 + ldsSt]);
    gload_lds16(gB + kt, &sh[4096 + ldsSt]);
    gload_lds16(gB + (size_t)64 * K + kt, &sh[4096 + 2048 + ldsSt]);
    __syncthreads();  // drains vmcnt(0): tile in LDS (TLP across 4 blocks hides this)
    s16x8 av[4], bv[4];
#pragma unroll
    for (int mf = 0; mf < 4; ++mf) av[mf] = *(const s16x8*)&sh[(arow + mf * 16) * 32 + koff];
#pragma unroll
    for (int nf = 0; nf < 4; ++nf) bv[nf] = *(const s16x8*)&sh[4096 + (brow + nf * 16) * 32 + koff];
#pragma unroll
    for (int mf = 0; mf < 4; ++mf)
#pragma unroll
      for (int nf = 0; nf < 4; ++nf)
        acc[mf][nf] = __builtin_amdgcn_mfma_f32_16x16x32_bf16(av[mf], bv[nf], acc[mf][nf], 0, 0, 0);
    __syncthreads();  // all reads done before next stage overwrites
  }

  // epilogue (C frag layout: col = lane&15, row = (lane>>4)*4 + reg)
  if (EPI == 0) {
    unsigned short* Hc = (unsigned short*)C;
#pragma unroll
    for (int mf = 0; mf < 4; ++mf) {
      int rowb = m0 + wm * 64 + mf * 16 + ((lane >> 4) << 2);
#pragma unroll
      for (int nf = 0; nf < 4; ++nf) {
        int col = n0 + wn * 64 + nf * 16 + (lane & 15);
#pragma unroll
        for (int r = 0; r < 4; ++r) {
          float v = acc[mf][nf][r];
          float g = 0.5f * v * (1.0f + erff(v * 0.70710678118654752f));
          Hc[(size_t)(rowb + r) * N + col] = f2bf(g);
        }
      }
    }
  } else {
    float* O = (float*)C;
#pragma unroll
    for (int mf = 0; mf < 4; ++mf) {
      int rowb = m0 + wm * 64 + mf * 16 + ((lane >> 4) << 2);
      int tk[4];
      float pv[4];
#pragma unroll
      for (int r = 0; r < 4; ++r) { tk[r] = sel_idx[rowb + r]; pv[r] = sel_p[rowb + r]; }
#pragma unroll
      for (int nf = 0; nf < 4; ++nf) {
        int col = n0 + wn * 64 + nf * 16 + (lane & 15);
#pragma unroll
        for (int r = 0; r < 4; ++r)
          atomicAdd(&O[(size_t)tk[r] * DMODEL + col], acc[mf][nf][r] * pv[r]);
      }
    }
  }
}

extern "C" void kernel_launch(void* const* d_in, const int* in_sizes, int n_in,
                              void* d_out, int out_size, void* d_ws, size_t ws_size,
                              hipStream_t stream) {
  const float* x  = (const float*)d_in[0];
  const float* Wg = (const float*)d_in[1];
  const float* bg = (const float*)d_in[2];
  const float* W1 = (const float*)d_in[3];
  const float* W2 = (const float*)d_in[4];
  float* out = (float*)d_out;

  char* ws = (char*)d_ws;
  unsigned long long* keys = (unsigned long long*)ws;            // 256 KiB
  int*   sel_idx = (int*)(ws + 262144);                          // 32 KiB
  float* sel_p   = (float*)(ws + 262144 + 32768);                // 32 KiB
  unsigned short* tok = (unsigned short*)(ws + 327680);          // 32 MiB
  const size_t tok_b = (size_t)N_TOK * DMODEL * 2;
  const size_t h_b   = (size_t)N_TOK * HDIM * 2;                 // 128 MiB
  const size_t w_b   = (size_t)NEXP * DMODEL * HDIM * 2;         // 128 MiB each
  const size_t base  = 327680 + tok_b;

  hipMemsetAsync(d_out, 0, (size_t)out_size * sizeof(float), stream);
  router_kernel<<<N_TOK / 4, 256, 0, stream>>>(x, Wg, bg, keys);
  rank_select_kernel<<<dim3(N_TOK / 256, NEXP), 256, 0, stream>>>(keys, sel_idx, sel_p);
  gather_kernel<<<NEXP * CAP, 256, 0, stream>>>(x, sel_idx, tok);

  if (ws_size >= base + h_b + 2 * w_b) {
    unsigned short* h   = (unsigned short*)(ws + base);
    unsigned short* W1T = (unsigned short*)(ws + base + h_b);
    unsigned short* W2T = (unsigned short*)(ws + base + h_b + w_b);
    transpose_convert_kernel<<<dim3(HDIM / 64, DMODEL / 64, NEXP), 256, 0, stream>>>(
        W1, W1T, DMODEL, HDIM);
    transpose_convert_kernel<<<dim3(DMODEL / 64, HDIM / 64, NEXP), 256, 0, stream>>>(
        W2, W2T, HDIM, DMODEL);
    gemm_kernel<0><<<dim3(HDIM / 128, N_TOK / 128), 256, 0, stream>>>(
        tok, W1T, h, nullptr, nullptr, N_TOK, HDIM, DMODEL, (size_t)DMODEL * HDIM);
    gemm_kernel<1><<<dim3(DMODEL / 128, N_TOK / 128), 256, 0, stream>>>(
        h, W2T, out, sel_idx, sel_p, N_TOK, DMODEL, HDIM, (size_t)DMODEL * HDIM);
  } else {
    unsigned short* h    = (unsigned short*)(ws + base);
    unsigned short* wbuf = (unsigned short*)(ws + base + (size_t)CAP * HDIM * 2);
    for (int e = 0; e < NEXP; ++e) {
      transpose_convert_kernel<<<dim3(HDIM / 64, DMODEL / 64, 1), 256, 0, stream>>>(
          W1 + (size_t)e * DMODEL * HDIM, wbuf, DMODEL, HDIM);
      gemm_kernel<0><<<dim3(HDIM / 128, CAP / 128), 256, 0, stream>>>(
          tok + (size_t)e * CAP * DMODEL, wbuf, h, nullptr, nullptr, CAP, HDIM, DMODEL, 0);
      transpose_convert_kernel<<<dim3(DMODEL / 64, HDIM / 64, 1), 256, 0, stream>>>(
          W2 + (size_t)e * HDIM * DMODEL, wbuf, HDIM, DMODEL);
      gemm_kernel<1><<<dim3(DMODEL / 128, CAP / 128), 256, 0, stream>>>(
          h, wbuf, out, sel_idx + e * CAP, sel_p + e * CAP, CAP, DMODEL, HDIM, 0);
    }
  }
}

// Round 11
// 867.698 us; speedup vs baseline: 1.3480x; 1.3480x over previous
//
#include <hip/hip_runtime.h>
#include <hip/hip_bf16.h>
#include <math.h>
#include <stdint.h>

// Problem constants: B=4, T=2048, D=2048, E=4, H=8192, TOPK=2, CAP=N/E
#define N_TOK 8192
#define DMODEL 2048
#define NEXP 4
#define HDIM 8192
#define CAP 2048

typedef __attribute__((ext_vector_type(4))) float f32x4;
typedef __attribute__((ext_vector_type(8))) short s16x8;
typedef __attribute__((ext_vector_type(4))) unsigned short u16x4;

__device__ __forceinline__ unsigned short f2bf(float f) {
  __hip_bfloat16 h = __float2bfloat16(f);  // RNE
  return __builtin_bit_cast(unsigned short, h);
}

__device__ __forceinline__ void gload_lds16(const void* g, void* l) {
  __builtin_amdgcn_global_load_lds(
      (const __attribute__((address_space(1))) unsigned int*)(uintptr_t)g,
      (__attribute__((address_space(3))) unsigned int*)(unsigned int)(uintptr_t)l,
      16, 0, 0);
}

// ---------------- Router: logits = x @ Wg + bg (f64 accum), top-2 -> 64-bit sort keys --------
__global__ __launch_bounds__(256) void router_kernel(
    const float* __restrict__ x, const float* __restrict__ Wg,
    const float* __restrict__ bg, unsigned long long* __restrict__ keys) {
  int token = blockIdx.x * 4 + (threadIdx.x >> 6);
  int lane = threadIdx.x & 63;
  const float* xr = x + (size_t)token * DMODEL;
  double a0 = 0, a1 = 0, a2 = 0, a3 = 0;
  for (int i = lane; i < DMODEL; i += 64) {
    float xv = xr[i];
    float4 w = ((const float4*)Wg)[i];
    a0 += (double)xv * (double)w.x;
    a1 += (double)xv * (double)w.y;
    a2 += (double)xv * (double)w.z;
    a3 += (double)xv * (double)w.w;
  }
  for (int off = 32; off > 0; off >>= 1) {
    a0 += __shfl_down(a0, off);
    a1 += __shfl_down(a1, off);
    a2 += __shfl_down(a2, off);
    a3 += __shfl_down(a3, off);
  }
  if (lane == 0) {
    float l[4] = {(float)(a0 + (double)bg[0]), (float)(a1 + (double)bg[1]),
                  (float)(a2 + (double)bg[2]), (float)(a3 + (double)bg[3])};
    int e1 = 0;
    for (int e = 1; e < 4; ++e) if (l[e] > l[e1]) e1 = e;
    int e2 = (e1 == 0) ? 1 : 0;
    for (int e = e2 + 1; e < 4; ++e) { if (e == e1) continue; if (l[e] > l[e2]) e2 = e; }
    float d = l[e2] - l[e1];
    float ex = expf(d);
    float z = 1.0f + ex;
    float p1 = 1.0f / z, p2 = ex / z;
    unsigned lo = 0xFFFFFFFFu - (unsigned)token;
    for (int e = 0; e < 4; ++e) {
      unsigned hi = (e == e1) ? __float_as_uint(p1) : (e == e2) ? __float_as_uint(p2) : 0u;
      keys[(size_t)e * N_TOK + token] = ((unsigned long long)hi << 32) | lo;
    }
  }
}

// ---------------- Rank-based capacity selection: slot = #{j : key_j > key_i} -----------------
__global__ __launch_bounds__(256) void rank_select_kernel(
    const unsigned long long* __restrict__ keys, int* __restrict__ sel_idx,
    float* __restrict__ sel_p) {
  __shared__ unsigned long long kbuf[2048];  // 16 KiB
  const int e = blockIdx.y;
  const int i = blockIdx.x * 256 + threadIdx.x;
  const unsigned long long my = keys[(size_t)e * N_TOK + i];
  int rank = 0;
  for (int c = 0; c < N_TOK; c += 2048) {
    __syncthreads();
    for (int j = threadIdx.x; j < 2048; j += 256)
      kbuf[j] = keys[(size_t)e * N_TOK + c + j];
    __syncthreads();
#pragma unroll 8
    for (int j = 0; j < 2048; j += 2) {
      unsigned long long k0 = kbuf[j], k1 = kbuf[j + 1];
      rank += (k0 > my) + (k1 > my);
    }
  }
  if (rank < CAP) {
    sel_idx[e * CAP + rank] = i;
    sel_p[e * CAP + rank] = __uint_as_float((unsigned)(my >> 32));
  }
}

// ---------------- Gather selected token rows, f32 -> bf16 ----------------
__global__ __launch_bounds__(256) void gather_kernel(
    const float* __restrict__ x, const int* __restrict__ sel_idx,
    unsigned short* __restrict__ tok) {
  int row = blockIdx.x;
  int t = sel_idx[row];
  const float4* src = (const float4*)(x + (size_t)t * DMODEL);
  u16x4* dst = (u16x4*)(tok + (size_t)row * DMODEL);
  for (int i = threadIdx.x; i < DMODEL / 4; i += blockDim.x) {
    float4 v = src[i];
    u16x4 w = {f2bf(v.x), f2bf(v.y), f2bf(v.z), f2bf(v.w)};
    dst[i] = w;
  }
}

// ---------------- Transpose + convert: W[K][N] f32 -> WT[N][K] bf16, 64x64 tiles ----------------
__global__ __launch_bounds__(256) void transpose_convert_kernel(
    const float* __restrict__ W, unsigned short* __restrict__ WT, int K, int N) {
  __shared__ unsigned short tile[64][68];
  const size_t eoff = (size_t)blockIdx.z * (size_t)K * N;
  const float* Wp = W + eoff;
  unsigned short* Tp = WT + eoff;
  const int n0 = blockIdx.x * 64, k0 = blockIdx.y * 64;
  const int tid = threadIdx.x;
  const int nn4 = tid & 15, kk = tid >> 4;
#pragma unroll
  for (int p = 0; p < 4; ++p) {
    int k = kk + p * 16;
    float4 v = *(const float4*)&Wp[(size_t)(k0 + k) * N + n0 + nn4 * 4];
    tile[nn4 * 4 + 0][k] = f2bf(v.x);
    tile[nn4 * 4 + 1][k] = f2bf(v.y);
    tile[nn4 * 4 + 2][k] = f2bf(v.z);
    tile[nn4 * 4 + 3][k] = f2bf(v.w);
  }
  __syncthreads();
  const int nw = tid >> 4, cw = (tid & 15) * 4;
#pragma unroll
  for (int p = 0; p < 4; ++p) {
    int n = nw + p * 16;
    u16x4 v = *(const u16x4*)&tile[n][cw];
    *(u16x4*)&Tp[(size_t)(n0 + n) * K + k0 + cw] = v;
  }
}

// ---------------- 256x256 double-buffered pipelined bf16 GEMM (r3 structure, best measured) --
// C[M,N] = A[M,K] * Bt[N,K]^T (both bf16, k-contiguous rows). 512 thr = 8 waves (2Mx4N),
// per-wave 128x64 output = acc[8][4]. BK=64. LDS 128 KiB: 2 x (A 256x64 + B 256x64).
// T2 swizzle both sides (measured 0 conflicts): global source chunk ^= row&7, read ^= row&7.
// Pipeline: prefetch tile t+1 (A at phase kb=0 start, B between kb=0/kb=1) into buf^1
// while computing tile t; single __syncthreads() (full vmcnt drain) per K-tile — the
// prefetch has the whole tile compute (~1.3K cyc) to land, covering HBM latency.
// Measured r3: 330 us/dispatch, MfmaUtil 37%, 0 bank conflicts. 7 "smarter" schedules
// (3-buf vmcnt, 4-slot, 8-phase x2, reg read-ahead, single-buf TLP) all measured slower.
// EPI 0: exact GELU -> bf16. EPI 1: atomicAdd(out[sel_idx[m]], acc*sel_p[m]).
template <int EPI>
__global__ __launch_bounds__(512) void gemm_kernel(
    const unsigned short* __restrict__ A, const unsigned short* __restrict__ Bt,
    void* __restrict__ C, const int* __restrict__ sel_idx, const float* __restrict__ sel_p,
    int M, int N, int K, size_t b_stride) {
  __shared__ unsigned short sh[65536];  // [buf][A/B][row 0..255][k 0..63] = 128 KiB
  const int tid = threadIdx.x;
  const int lane = tid & 63;
  const int w = tid >> 6;          // wave 0..7
  const int wm = w >> 2, wn = w & 3;

  // XCD-aware bijective swizzle (grid sizes here are multiples of 8)
  const int nwg = gridDim.x * gridDim.y;
  const int cpx = nwg >> 3;
  int linear = blockIdx.y * gridDim.x + blockIdx.x;
  linear = (linear & 7) * cpx + (linear >> 3);
  const int bx = linear & (gridDim.x - 1);
  const int by = linear >> __builtin_ctz(gridDim.x);
  const int m0 = by * 256, n0 = bx * 256;
  const unsigned short* Bp = Bt + (size_t)(m0 >> 11) * b_stride;

  f32x4 acc[8][4];
#pragma unroll
  for (int i = 0; i < 8; ++i)
#pragma unroll
    for (int j = 0; j < 4; ++j) acc[i][j] = (f32x4){0.f, 0.f, 0.f, 0.f};

  // staging addressing: wave w stages rows [w*32, w*32+32) of A and of B.
  // lane -> row_off = lane>>3, chunk_g = (lane&7) ^ (lane>>3)  (inverse swizzle on source)
  const int srow = w * 32 + (lane >> 3);
  const int schunk = ((lane & 7) ^ (lane >> 3)) * 8;
  const unsigned short* gA = A + (size_t)(m0 + srow) * K + schunk;
  const unsigned short* gB = Bp + (size_t)(n0 + srow) * K + schunk;
  const int ldsA = w * 2048;            // ushort index of wave's A slice base
  const int ldsB = 16384 + w * 2048;    // B slice base

  // read addressing: swizzled k-chunk (ushort units), csw1 = csw0 ^ 32
  const int csw0 = (((lane >> 4) ^ (lane & 7)) << 3);
  const int arow = wm * 128 + (lane & 15);  // A frag base row (+ mf*16)
  const int brow = wn * 64 + (lane & 15);   // B frag base row (+ nf*16)

  // prologue: stage tile 0 into buf 0
#pragma unroll
  for (int i = 0; i < 4; ++i) {
    gload_lds16(gA + (size_t)(i * 8) * K, &sh[ldsA + i * 512]);
    gload_lds16(gB + (size_t)(i * 8) * K, &sh[ldsB + i * 512]);
  }
  __syncthreads();

  int buf = 0;
  for (int kt = 0; kt < K; kt += 64, buf ^= 1) {
    const int nb = buf ^ 1;
    const unsigned short* shA = &sh[buf * 32768];
    const unsigned short* shB = &sh[buf * 32768 + 16384];
    const bool pf = (kt + 64) < K;
    // ---- phase 0 (kb=0): issue A-prefetch, then compute ----
    if (pf) {
#pragma unroll
      for (int i = 0; i < 4; ++i)
        gload_lds16(gA + (size_t)(i * 8) * K + (kt + 64), &sh[nb * 32768 + ldsA + i * 512]);
    }
#pragma unroll
    for (int kb = 0; kb < 2; ++kb) {
      const int csw = csw0 ^ (kb << 5);
      s16x8 av[8], bv[4];
#pragma unroll
      for (int mf = 0; mf < 8; ++mf)
        av[mf] = *(const s16x8*)&shA[(arow + mf * 16) * 64 + csw];
#pragma unroll
      for (int nf = 0; nf < 4; ++nf)
        bv[nf] = *(const s16x8*)&shB[(brow + nf * 16) * 64 + csw];
      __builtin_amdgcn_s_setprio(1);
#pragma unroll
      for (int mf = 0; mf < 8; ++mf)
#pragma unroll
        for (int nf = 0; nf < 4; ++nf)
          acc[mf][nf] = __builtin_amdgcn_mfma_f32_16x16x32_bf16(av[mf], bv[nf], acc[mf][nf], 0, 0, 0);
      __builtin_amdgcn_s_setprio(0);
      // ---- between phases: issue B-prefetch ----
      if (kb == 0 && pf) {
#pragma unroll
        for (int i = 0; i < 4; ++i)
          gload_lds16(gB + (size_t)(i * 8) * K + (kt + 64), &sh[nb * 32768 + ldsB + i * 512]);
      }
    }
    __syncthreads();  // drains vmcnt(0): prefetched tile fully in LDS, all reads done
  }

  // epilogue (C frag layout: col = lane&15, row = (lane>>4)*4 + reg)
  if (EPI == 0) {
    unsigned short* Hc = (unsigned short*)C;
#pragma unroll
    for (int mf = 0; mf < 8; ++mf) {
      int rowb = m0 + wm * 128 + mf * 16 + ((lane >> 4) << 2);
#pragma unroll
      for (int nf = 0; nf < 4; ++nf) {
        int col = n0 + wn * 64 + nf * 16 + (lane & 15);
#pragma unroll
        for (int r = 0; r < 4; ++r) {
          float v = acc[mf][nf][r];
          float g = 0.5f * v * (1.0f + erff(v * 0.70710678118654752f));
          Hc[(size_t)(rowb + r) * N + col] = f2bf(g);
        }
      }
    }
  } else {
    float* O = (float*)C;
#pragma unroll
    for (int mf = 0; mf < 8; ++mf) {
      int rowb = m0 + wm * 128 + mf * 16 + ((lane >> 4) << 2);
      int tk[4];
      float pv[4];
#pragma unroll
      for (int r = 0; r < 4; ++r) { tk[r] = sel_idx[rowb + r]; pv[r] = sel_p[rowb + r]; }
#pragma unroll
      for (int nf = 0; nf < 4; ++nf) {
        int col = n0 + wn * 64 + nf * 16 + (lane & 15);
#pragma unroll
        for (int r = 0; r < 4; ++r)
          atomicAdd(&O[(size_t)tk[r] * DMODEL + col], acc[mf][nf][r] * pv[r]);
      }
    }
  }
}

extern "C" void kernel_launch(void* const* d_in, const int* in_sizes, int n_in,
                              void* d_out, int out_size, void* d_ws, size_t ws_size,
                              hipStream_t stream) {
  const float* x  = (const float*)d_in[0];
  const float* Wg = (const float*)d_in[1];
  const float* bg = (const float*)d_in[2];
  const float* W1 = (const float*)d_in[3];
  const float* W2 = (const float*)d_in[4];
  float* out = (float*)d_out;

  char* ws = (char*)d_ws;
  unsigned long long* keys = (unsigned long long*)ws;            // 256 KiB
  int*   sel_idx = (int*)(ws + 262144);                          // 32 KiB
  float* sel_p   = (float*)(ws + 262144 + 32768);                // 32 KiB
  unsigned short* tok = (unsigned short*)(ws + 327680);          // 32 MiB
  const size_t tok_b = (size_t)N_TOK * DMODEL * 2;
  const size_t h_b   = (size_t)N_TOK * HDIM * 2;                 // 128 MiB
  const size_t w_b   = (size_t)NEXP * DMODEL * HDIM * 2;         // 128 MiB each
  const size_t base  = 327680 + tok_b;

  hipMemsetAsync(d_out, 0, (size_t)out_size * sizeof(float), stream);
  router_kernel<<<N_TOK / 4, 256, 0, stream>>>(x, Wg, bg, keys);
  rank_select_kernel<<<dim3(N_TOK / 256, NEXP), 256, 0, stream>>>(keys, sel_idx, sel_p);
  gather_kernel<<<NEXP * CAP, 256, 0, stream>>>(x, sel_idx, tok);

  if (ws_size >= base + h_b + 2 * w_b) {
    // Merged path: one dispatch per GEMM stage across all 4 experts.
    unsigned short* h   = (unsigned short*)(ws + base);
    unsigned short* W1T = (unsigned short*)(ws + base + h_b);
    unsigned short* W2T = (unsigned short*)(ws + base + h_b + w_b);
    transpose_convert_kernel<<<dim3(HDIM / 64, DMODEL / 64, NEXP), 256, 0, stream>>>(
        W1, W1T, DMODEL, HDIM);
    transpose_convert_kernel<<<dim3(DMODEL / 64, HDIM / 64, NEXP), 256, 0, stream>>>(
        W2, W2T, HDIM, DMODEL);
    gemm_kernel<0><<<dim3(HDIM / 256, N_TOK / 256), 512, 0, stream>>>(
        tok, W1T, h, nullptr, nullptr, N_TOK, HDIM, DMODEL, (size_t)DMODEL * HDIM);
    gemm_kernel<1><<<dim3(DMODEL / 256, N_TOK / 256), 512, 0, stream>>>(
        h, W2T, out, sel_idx, sel_p, N_TOK, DMODEL, HDIM, (size_t)DMODEL * HDIM);
  } else {
    // Fallback: per-expert, reuse one weight buffer + one h buffer.
    unsigned short* h    = (unsigned short*)(ws + base);                 // CAPxHDIM = 32 MiB
    unsigned short* wbuf = (unsigned short*)(ws + base + (size_t)CAP * HDIM * 2);
    for (int e = 0; e < NEXP; ++e) {
      transpose_convert_kernel<<<dim3(HDIM / 64, DMODEL / 64, 1), 256, 0, stream>>>(
          W1 + (size_t)e * DMODEL * HDIM, wbuf, DMODEL, HDIM);
      gemm_kernel<0><<<dim3(HDIM / 256, CAP / 256), 512, 0, stream>>>(
          tok + (size_t)e * CAP * DMODEL, wbuf, h, nullptr, nullptr, CAP, HDIM, DMODEL, 0);
      transpose_convert_kernel<<<dim3(DMODEL / 64, HDIM / 64, 1), 256, 0, stream>>>(
          W2 + (size_t)e * HDIM * DMODEL, wbuf, HDIM, DMODEL);
      gemm_kernel<1><<<dim3(DMODEL / 256, CAP / 256), 512, 0, stream>>>(
          h, wbuf, out, sel_idx + e * CAP, sel_p + e * CAP, CAP, DMODEL, HDIM, 0);
    }
  }
}